// Round 1
// baseline (650.135 us; speedup 1.0000x reference)
//
#include <hip/hip_runtime.h>

// BlockEnd: out[b,a,f] = (a < M[b]) ? relu( sum_r resid[b,a,r]*w[r,f] + node[b,a,f] ) : 0
// B=4096, A=RF=F=128. fp32 in/out; compute via bf16 MFMA.
//
// R1 theory: previous version (32 rows/wave, acc[2][8]=64 AGPR + 76 VGPR = ~140
// unified regs) was latency-bound: 3 waves/SIMD, serial load->cvt->mfma->epilogue
// phases, 2.4 TB/s (39% of achievable). This version:
//  - 16 rows per wave (acc = 32 regs), 8192 blocks x 4 waves, __launch_bounds__(256,4)
//    -> >=4 waves/SIMD and more arch regs for the scheduler to pipeline loads.
//  - all 8 resid loads issued up front (independent); ft-loop streams
//    mfma -> node load -> relu -> store so node loads overlap compute.
//  - inactive lanes (a >= M) clamp their load row to row 0: branchless, dead-row
//    reads become L1 hits instead of HBM fetch.
//  - nontemporal stores for out (write-once, never re-read) to keep streamed
//    inputs resident in L2/L3.

typedef __bf16 bf16x8 __attribute__((ext_vector_type(8)));
typedef float f32x4 __attribute__((ext_vector_type(4)));

static_assert(sizeof(bf16x8) == 16, "bf16x8 must be 16B");
static_assert(sizeof(f32x4) == 16, "f32x4 must be 16B");

// wT[f*128 + r] = (bf16) w[r*128 + f].
__global__ __launch_bounds__(256) void wT_kernel(const float* __restrict__ w,
                                                 __bf16* __restrict__ wT) {
    int i = blockIdx.x * 256 + threadIdx.x;   // 0..16383
    int f = i >> 7;
    int r = i & 127;
    wT[i] = (__bf16)w[r * 128 + f];
}

__global__ __launch_bounds__(256, 4) void blockend_kernel(
    const float* __restrict__ node,    // [B,128,128]
    const float* __restrict__ resid,   // [B,128,128]
    const __bf16* __restrict__ wT,     // [128(f),128(r)] bf16
    const int*   __restrict__ mol,     // [B,2] int32 pairs (low word of int64), M = mol[2b]
    float*       __restrict__ out)     // [B,128,128]
{
    const int bb   = blockIdx.x;       // 0..8191: two blocks per molecule
    const int b    = bb >> 1;
    const int t    = threadIdx.x;
    const int wave = t >> 6;
    const int lane = t & 63;
    const int quad = lane >> 4;
    const int m16  = lane & 15;

    const int M      = mol[2 * b];
    const int a_base = (bb & 1) * 64 + wave * 16;   // 16-row wave tile

    const size_t base = (size_t)b * (128 * 128);
    float* outW = out + base + (size_t)a_base * 128;

    if (M <= a_base) {
        // whole wave masked: 16 rows x 128 cols of zeros, coalesced float4, NT
        f32x4 z = {0.f, 0.f, 0.f, 0.f};
#pragma unroll
        for (int it = 0; it < 8; ++it)
            __builtin_nontemporal_store(z, (f32x4*)outW + it * 64 + lane);
        return;
    }

    // Per-lane row mask. Inactive lanes clamp their load row to local row 0
    // (a_base < M, so it's always valid) -> duplicate reads hit L1, cost ~0 HBM.
    const bool active = (a_base + m16) < M;
    const int  rrow   = active ? m16 : 0;

    const float* residW = resid + base + (size_t)a_base * 128;
    const float* nodeW  = node  + base + (size_t)a_base * 128;

    // All 8 resid loads (4 kk x {lo,hi}) issued up front — independent, deep MLP.
    // B-operand fragment: resid[a = a_base + m16][k = kk*32 + quad*8 + j], f32->bf16.
    bf16x8 rfrag[4];
#pragma unroll
    for (int kk = 0; kk < 4; ++kk) {
        const float* ap = residW + rrow * 128 + kk * 32 + quad * 8;
        f32x4 lo = *(const f32x4*)ap;
        f32x4 hi = *(const f32x4*)(ap + 4);
        bf16x8 v;
        v[0] = (__bf16)lo[0]; v[1] = (__bf16)lo[1];
        v[2] = (__bf16)lo[2]; v[3] = (__bf16)lo[3];
        v[4] = (__bf16)hi[0]; v[5] = (__bf16)hi[1];
        v[6] = (__bf16)hi[2]; v[7] = (__bf16)hi[3];
        rfrag[kk] = v;
    }

    // Stream over f-tiles: 4 MFMAs -> node load -> relu -> NT store per tile.
    // C layout (A=wT so m->f): f = ft*16 + quad*4 + reg, a = m16.
#pragma unroll
    for (int ft = 0; ft < 8; ++ft) {
        f32x4 acc = {0.f, 0.f, 0.f, 0.f};
#pragma unroll
        for (int kk = 0; kk < 4; ++kk) {
            bf16x8 wfrag = *(const bf16x8*)(wT + (ft * 16 + m16) * 128 + kk * 32 + quad * 8);
            acc = __builtin_amdgcn_mfma_f32_16x16x32_bf16(wfrag, rfrag[kk], acc, 0, 0, 0);
        }
        const int offs = ft * 16 + quad * 4;
        f32x4 nd = *(const f32x4*)(nodeW + rrow * 128 + offs);
        f32x4 v;
#pragma unroll
        for (int i = 0; i < 4; ++i) {
            float x = acc[i] + nd[i];
            v[i] = (active && x > 0.f) ? x : 0.f;
        }
        __builtin_nontemporal_store(v, (f32x4*)(outW + m16 * 128 + offs));
    }
}

extern "C" void kernel_launch(void* const* d_in, const int* in_sizes, int n_in,
                              void* d_out, int out_size, void* d_ws, size_t ws_size,
                              hipStream_t stream) {
    const float* node  = (const float*)d_in[0];   // node_features    [4096,128,128]
    const float* resid = (const float*)d_in[1];   // residual_features[4096,128,128]
    const float* w     = (const float*)d_in[2];   // w [128,128]
    const int*   mol   = (const int*)d_in[3];     // mol_slice [4096,2] int64 -> int32 pairs
    float*       out   = (float*)d_out;
    __bf16*      wT    = (__bf16*)d_ws;           // 32 KB scratch

    wT_kernel<<<64, 256, 0, stream>>>(w, wT);
    blockend_kernel<<<8192, 256, 0, stream>>>(node, resid, wT, mol, out);
}

// Round 3
// 616.141 us; speedup vs baseline: 1.0552x; 1.0552x over previous
//
#include <hip/hip_runtime.h>

// BlockEnd: out[b,a,f] = (a < M[b]) ? relu( sum_r resid[b,a,r]*w[r,f] + node[b,a,f] ) : 0
// B=4096, A=RF=F=128. fp32 in/out; compute via bf16 MFMA.
//
// R2 theory (resubmitted R3 after broker timeout): R1 regressed (257us vs R0
// 173us) because the compiler sank the node loads to their use sites inside
// the per-ft loop -> 8 serial HBM round-trips per wave (VGPR_Count=36 = no
// pipelining). Occupancy was NOT the constraint (41% with BW *down*). Fix:
// issue ALL 16 HBM loads (8 resid + 8 node f32x4) up-front into registers,
// pinned with an empty asm so they can't sink; ft-loop then runs from regs +
// L2-resident wT only. Also revert NT stores (they defeated L2
// write-combining: WRITE_SIZE 263->290 MB).

typedef __bf16 bf16x8 __attribute__((ext_vector_type(8)));
typedef float f32x4 __attribute__((ext_vector_type(4)));

static_assert(sizeof(bf16x8) == 16, "bf16x8 must be 16B");
static_assert(sizeof(f32x4) == 16, "f32x4 must be 16B");

// wT[f*128 + r] = (bf16) w[r*128 + f].
__global__ __launch_bounds__(256) void wT_kernel(const float* __restrict__ w,
                                                 __bf16* __restrict__ wT) {
    int i = blockIdx.x * 256 + threadIdx.x;   // 0..16383
    int f = i >> 7;
    int r = i & 127;
    wT[i] = (__bf16)w[r * 128 + f];
}

__global__ __launch_bounds__(256, 4) void blockend_kernel(
    const float* __restrict__ node,    // [B,128,128]
    const float* __restrict__ resid,   // [B,128,128]
    const __bf16* __restrict__ wT,     // [128(f),128(r)] bf16
    const int*   __restrict__ mol,     // [B,2] int32 pairs (low word of int64), M = mol[2b]
    float*       __restrict__ out)     // [B,128,128]
{
    const int bb   = blockIdx.x;       // 0..8191: two blocks per molecule
    const int b    = bb >> 1;
    const int t    = threadIdx.x;
    const int wave = t >> 6;
    const int lane = t & 63;
    const int quad = lane >> 4;
    const int m16  = lane & 15;

    const int M      = mol[2 * b];
    const int a_base = (bb & 1) * 64 + wave * 16;   // 16-row wave tile

    const size_t base = (size_t)b * (128 * 128);
    float* outW = out + base + (size_t)a_base * 128;

    if (M <= a_base) {
        // whole wave masked: 16 rows x 128 cols of zeros, coalesced float4
        f32x4 z = {0.f, 0.f, 0.f, 0.f};
        f32x4* p = (f32x4*)outW;
#pragma unroll
        for (int it = 0; it < 8; ++it)
            p[it * 64 + lane] = z;
        return;
    }

    // Per-lane row mask. Inactive lanes clamp their load row to local row 0
    // (a_base < M, so always valid) -> duplicate reads hit L1, ~0 extra HBM.
    const bool active = (a_base + m16) < M;
    const int  rrow   = active ? m16 : 0;

    const float* rowR = resid + base + (size_t)(a_base + rrow) * 128;
    const float* rowN = node  + base + (size_t)(a_base + rrow) * 128;

    // ---- Phase 1: issue ALL 16 HBM loads up-front (max MLP per wave) ----
    f32x4 rlo[4], rhi[4];
#pragma unroll
    for (int kk = 0; kk < 4; ++kk) {
        const float* ap = rowR + kk * 32 + quad * 8;
        rlo[kk] = *(const f32x4*)ap;
        rhi[kk] = *(const f32x4*)(ap + 4);
    }
    f32x4 nd[8];
#pragma unroll
    for (int ft = 0; ft < 8; ++ft)
        nd[ft] = *(const f32x4*)(rowN + ft * 16 + quad * 4);

    // Pin the node values in registers HERE so the scheduler cannot sink the
    // loads into the epilogue (R1's failure mode).
#pragma unroll
    for (int ft = 0; ft < 8; ++ft)
        asm volatile("" : "+v"(nd[ft]));

    // ---- Phase 2: f32 -> bf16 fragments (needs only the resid loads) ----
    // B-operand fragment: resid[a = a_base + m16][k = kk*32 + quad*8 + j]
    bf16x8 rfrag[4];
#pragma unroll
    for (int kk = 0; kk < 4; ++kk) {
        bf16x8 v;
        v[0] = (__bf16)rlo[kk][0]; v[1] = (__bf16)rlo[kk][1];
        v[2] = (__bf16)rlo[kk][2]; v[3] = (__bf16)rlo[kk][3];
        v[4] = (__bf16)rhi[kk][0]; v[5] = (__bf16)rhi[kk][1];
        v[6] = (__bf16)rhi[kk][2]; v[7] = (__bf16)rhi[kk][3];
        rfrag[kk] = v;
    }

    // ---- Phase 3: per f-tile: 4 wT loads (L2-hit) + 4 MFMA + fused epilogue.
    // C layout (A=wT so m->f): f = ft*16 + quad*4 + reg, a = m16.
#pragma unroll
    for (int ft = 0; ft < 8; ++ft) {
        f32x4 acc = {0.f, 0.f, 0.f, 0.f};
#pragma unroll
        for (int kk = 0; kk < 4; ++kk) {
            bf16x8 wfrag = *(const bf16x8*)(wT + (ft * 16 + m16) * 128 + kk * 32 + quad * 8);
            acc = __builtin_amdgcn_mfma_f32_16x16x32_bf16(wfrag, rfrag[kk], acc, 0, 0, 0);
        }
        const int offs = ft * 16 + quad * 4;
        f32x4 v;
#pragma unroll
        for (int i = 0; i < 4; ++i) {
            float x = acc[i] + nd[ft][i];
            v[i] = (active && x > 0.f) ? x : 0.f;
        }
        *(f32x4*)(outW + m16 * 128 + offs) = v;
    }
}

extern "C" void kernel_launch(void* const* d_in, const int* in_sizes, int n_in,
                              void* d_out, int out_size, void* d_ws, size_t ws_size,
                              hipStream_t stream) {
    const float* node  = (const float*)d_in[0];   // node_features    [4096,128,128]
    const float* resid = (const float*)d_in[1];   // residual_features[4096,128,128]
    const float* w     = (const float*)d_in[2];   // w [128,128]
    const int*   mol   = (const int*)d_in[3];     // mol_slice [4096,2] int64 -> int32 pairs
    float*       out   = (float*)d_out;
    __bf16*      wT    = (__bf16*)d_ws;           // 32 KB scratch

    wT_kernel<<<64, 256, 0, stream>>>(w, wT);
    blockend_kernel<<<8192, 256, 0, stream>>>(node, resid, wT, mol, out);
}

// Round 4
// 551.232 us; speedup vs baseline: 1.1794x; 1.1178x over previous
//
#include <hip/hip_runtime.h>

// BlockEnd: out[b,a,f] = (a < M[b]) ? relu( sum_r resid[b,a,r]*w[r,f] + node[b,a,f] ) : 0
// B=4096, A=RF=F=128. fp32 in/out; compute via bf16 MFMA (16x16x32).
//
// R4 theory: R0(32-row)=173us beat both 16-row variants (257/216us). The
// dominant stall is the per-ft wT-from-L2 dependent chain (8 x ~250cy per
// wave) plus 32KB/wave of L2 wT traffic; occupancy was never the lever
// (MfmaUtil/VALUBusy <3% everywhere). Fix: stage wT in LDS once per block
// (32-row waves, 1 block/molecule). wT is stored PRE-SWIZZLED by the pre-pass
// (16B-unit column ^ (f&7)) so LDS writes are linear+conflict-free and the
// swizzled ds_read_b128 is 2-way (=free, m136). All resid + nt0-node loads
// issue before __syncthreads (barrier vmcnt drain overlaps staging); nt1-node
// loads issue after MFMA to hide under the nt0 store stream.

typedef __bf16 bf16x8 __attribute__((ext_vector_type(8)));
typedef float f32x4 __attribute__((ext_vector_type(4)));

static_assert(sizeof(bf16x8) == 16, "bf16x8 must be 16B");
static_assert(sizeof(f32x4) == 16, "f32x4 must be 16B");

// wTs: f-major bf16 weights, pre-swizzled so a LINEAR copy into LDS yields the
// XOR-swizzled layout: 16B unit (f, cu) holds wT_logical[f][(cu^(f&7))*8 .. +7].
__global__ __launch_bounds__(256) void wT_kernel(const float* __restrict__ w,
                                                 __bf16* __restrict__ wTs) {
    int i  = blockIdx.x * 256 + threadIdx.x;  // 0..16383 = f*128 + k
    int f  = i >> 7;
    int k  = i & 127;
    int cu = k >> 3;
    int j  = k & 7;
    int r  = ((cu ^ (f & 7)) << 3) | j;
    wTs[i] = (__bf16)w[r * 128 + f];
}

__global__ __launch_bounds__(256, 3) void blockend_kernel(
    const float* __restrict__ node,    // [B,128,128]
    const float* __restrict__ resid,   // [B,128,128]
    const __bf16* __restrict__ wTs,    // [128(f),128(r)] bf16, pre-swizzled
    const int*   __restrict__ mol,     // [B,2] int32 pairs (low word of int64)
    float*       __restrict__ out)     // [B,128,128]
{
    __shared__ __align__(16) unsigned char lds[32768];

    const int b    = blockIdx.x;       // one block per molecule
    const int t    = threadIdx.x;
    const int wave = t >> 6;
    const int lane = t & 63;
    const int quad = lane >> 4;
    const int m16  = lane & 15;

    const int M       = mol[2 * b];
    const int a_base  = wave * 32;     // 32-row wave tile
    const size_t base = (size_t)b * (128 * 128);

    // ---- stage pre-swizzled weights -> LDS: linear dest, conflict-free ----
#pragma unroll
    for (int i = 0; i < 8; ++i) {
        bf16x8 v = *(const bf16x8*)(wTs + (i * 256 + t) * 8);
        *(bf16x8*)(lds + i * 4096 + t * 16) = v;
    }

    const bool worker = (M > a_base);

    // Inactive lanes clamp their load row to wave row 0 (valid: a_base < M for
    // workers) -> duplicate reads are L1 hits, ~0 extra HBM.
    bool act0 = false, act1 = false;
    int  rr0 = 0, rr1 = 0;
    f32x4 rl[2][4], rh[2][4];
    f32x4 nd0[8];

    if (worker) {
        act0 = (a_base + m16) < M;
        act1 = (a_base + 16 + m16) < M;
        rr0  = act0 ? m16        : 0;
        rr1  = act1 ? (16 + m16) : 0;

        const float* rowR0 = resid + base + (size_t)(a_base + rr0) * 128;
        const float* rowR1 = resid + base + (size_t)(a_base + rr1) * 128;
#pragma unroll
        for (int kk = 0; kk < 4; ++kk) {
            rl[0][kk] = *(const f32x4*)(rowR0 + kk * 32 + quad * 8);
            rh[0][kk] = *(const f32x4*)(rowR0 + kk * 32 + quad * 8 + 4);
            rl[1][kk] = *(const f32x4*)(rowR1 + kk * 32 + quad * 8);
            rh[1][kk] = *(const f32x4*)(rowR1 + kk * 32 + quad * 8 + 4);
        }
        const float* rowN0 = node + base + (size_t)(a_base + rr0) * 128;
#pragma unroll
        for (int ft = 0; ft < 8; ++ft)
            nd0[ft] = *(const f32x4*)(rowN0 + ft * 16 + quad * 4);

        // Pin so the loads cannot sink below the barrier (R1 failure mode).
#pragma unroll
        for (int kk = 0; kk < 4; ++kk)
            asm volatile("" : "+v"(rl[0][kk]), "+v"(rh[0][kk]),
                              "+v"(rl[1][kk]), "+v"(rh[1][kk]));
#pragma unroll
        for (int ft = 0; ft < 8; ++ft)
            asm volatile("" : "+v"(nd0[ft]));
    }

    __syncthreads();   // also drains the global loads issued above (free overlap)

    float* outW = out + base + (size_t)a_base * 128;

    if (!worker) {
        // whole wave masked: 32 rows x 128 cols of zeros, coalesced float4
        f32x4 z = {0.f, 0.f, 0.f, 0.f};
        f32x4* p = (f32x4*)outW;
#pragma unroll
        for (int it = 0; it < 16; ++it)
            p[it * 64 + lane] = z;
        return;
    }

    // ---- f32 -> bf16 B-operand fragments ----
    bf16x8 rfrag[2][4];
#pragma unroll
    for (int nt = 0; nt < 2; ++nt)
#pragma unroll
        for (int kk = 0; kk < 4; ++kk) {
            bf16x8 v;
            v[0] = (__bf16)rl[nt][kk][0]; v[1] = (__bf16)rl[nt][kk][1];
            v[2] = (__bf16)rl[nt][kk][2]; v[3] = (__bf16)rl[nt][kk][3];
            v[4] = (__bf16)rh[nt][kk][0]; v[5] = (__bf16)rh[nt][kk][1];
            v[6] = (__bf16)rh[nt][kk][2]; v[7] = (__bf16)rh[nt][kk][3];
            rfrag[nt][kk] = v;
        }

    // ---- LDS read addresses (swizzled; rows r and r+8 alias = 2-way = free) ----
    const int xr = m16 & 7;
    int raddr[4];
#pragma unroll
    for (int kk = 0; kk < 4; ++kk)
        raddr[kk] = m16 * 256 + ((((kk << 2) | quad) ^ xr) << 4);

    f32x4 acc[2][8];
#pragma unroll
    for (int nt = 0; nt < 2; ++nt)
#pragma unroll
        for (int ft = 0; ft < 8; ++ft)
            acc[nt][ft] = (f32x4){0.f, 0.f, 0.f, 0.f};

    // ---- MFMA loop: wfrag from LDS, reused across both nt sub-tiles ----
#pragma unroll
    for (int ft = 0; ft < 8; ++ft) {
#pragma unroll
        for (int kk = 0; kk < 4; ++kk) {
            bf16x8 wfrag = *(const bf16x8*)(lds + ft * 4096 + raddr[kk]);
            acc[0][ft] = __builtin_amdgcn_mfma_f32_16x16x32_bf16(
                wfrag, rfrag[0][kk], acc[0][ft], 0, 0, 0);
            acc[1][ft] = __builtin_amdgcn_mfma_f32_16x16x32_bf16(
                wfrag, rfrag[1][kk], acc[1][ft], 0, 0, 0);
        }
    }

    // ---- epilogue: issue nt1 node loads first (hide under nt0 stores) ----
    f32x4 nd1[8];
    const float* rowN1 = node + base + (size_t)(a_base + rr1) * 128;
#pragma unroll
    for (int ft = 0; ft < 8; ++ft)
        nd1[ft] = *(const f32x4*)(rowN1 + ft * 16 + quad * 4);
#pragma unroll
    for (int ft = 0; ft < 8; ++ft)
        asm volatile("" : "+v"(nd1[ft]));

    // C layout (A=wT so m->f): f = ft*16 + quad*4 + reg, a = m16 (+ nt*16).
#pragma unroll
    for (int ft = 0; ft < 8; ++ft) {
        const int off = m16 * 128 + ft * 16 + quad * 4;
        f32x4 v;
#pragma unroll
        for (int i = 0; i < 4; ++i) {
            float x = acc[0][ft][i] + nd0[ft][i];
            v[i] = (act0 && x > 0.f) ? x : 0.f;
        }
        *(f32x4*)(outW + off) = v;
    }
#pragma unroll
    for (int ft = 0; ft < 8; ++ft) {
        const int off = (16 + m16) * 128 + ft * 16 + quad * 4;
        f32x4 v;
#pragma unroll
        for (int i = 0; i < 4; ++i) {
            float x = acc[1][ft][i] + nd1[ft][i];
            v[i] = (act1 && x > 0.f) ? x : 0.f;
        }
        *(f32x4*)(outW + off) = v;
    }
}

extern "C" void kernel_launch(void* const* d_in, const int* in_sizes, int n_in,
                              void* d_out, int out_size, void* d_ws, size_t ws_size,
                              hipStream_t stream) {
    const float* node  = (const float*)d_in[0];   // node_features    [4096,128,128]
    const float* resid = (const float*)d_in[1];   // residual_features[4096,128,128]
    const float* w     = (const float*)d_in[2];   // w [128,128]
    const int*   mol   = (const int*)d_in[3];     // mol_slice [4096,2] int64 -> int32 pairs
    float*       out   = (float*)d_out;
    __bf16*      wTs   = (__bf16*)d_ws;           // 32 KB scratch (pre-swizzled)

    wT_kernel<<<64, 256, 0, stream>>>(w, wTs);
    blockend_kernel<<<4096, 256, 0, stream>>>(node, resid, wTs, mol, out);
}